// Round 13
// baseline (709.225 us; speedup 1.0000x reference)
//
#include <hip/hip_runtime.h>
#include <hip/hip_bf16.h>
#include <hip/hip_cooperative_groups.h>

namespace cg = cooperative_groups;

#define D 64
#define CLAMP_V -10000.0f
#define SBSHIFT 9           // super-bucket = 512 nodes (dst >> 9)
#define SBN 512
#define MAXSB 256           // static bound; runtime nbSB = ceil(100k/512) = 196
#define SCHUNK 2048         // edges per scatter chunk
#define NPW 8               // nodes per wave in seg phase
#define GRIDC 1024          // cooperative grid: 4 blocks/CU guaranteed

typedef __bf16 bf16x4 __attribute__((ext_vector_type(4)));
typedef __bf16 bf16x8 __attribute__((ext_vector_type(8)));
typedef float floatx4 __attribute__((ext_vector_type(4)));
typedef unsigned short u16x2 __attribute__((ext_vector_type(2)));
typedef short s16x2 __attribute__((ext_vector_type(2)));

__device__ __forceinline__ unsigned pkmax(unsigned a, unsigned b) {
    u16x2 r = __builtin_elementwise_max(__builtin_bit_cast(u16x2, a),
                                        __builtin_bit_cast(u16x2, b));
    return __builtin_bit_cast(unsigned, r);
}
__device__ __forceinline__ unsigned pk_ord_encode(unsigned g) {
    s16x2 t = __builtin_bit_cast(s16x2, g) >> 15;
    unsigned m = __builtin_bit_cast(unsigned, t) & 0x7FFF7FFFu;
    return g ^ (m | 0x80008000u);
}
__device__ __forceinline__ unsigned pk_ord_decode(unsigned e) {
    s16x2 t = __builtin_bit_cast(s16x2, e) >> 15;
    unsigned m = (~__builtin_bit_cast(unsigned, t)) & 0x7FFF7FFFu;
    return e ^ (m | 0x80008000u);
}

union SharedU {
    unsigned ts[256];
    struct {
        unsigned cop[MAXSB];            // cnt low16, off high16
        unsigned short lb16[MAXSB];
        unsigned gbase[MAXSB];
        unsigned payload[SCHUNK];       // 8 KB
        unsigned char sbid[SCHUNK];     // 2 KB
        unsigned ts2[256];
    } p3;                               // 13.8 KB total
    unsigned cur[SBN];                  // 2 KB
};

// ---------------- the fused cooperative pipeline ----------------
__global__ __launch_bounds__(256, 4) void fused_kernel(
        const float* __restrict__ nf, __bf16* __restrict__ nf16,
        const int* __restrict__ src, const int* __restrict__ dst,
        const float* __restrict__ W, __bf16* __restrict__ wfrag,
        unsigned* __restrict__ nodecnt,     // zeroed; nbSB*SBN entries
        unsigned* __restrict__ nodestart,   // nbSB*SBN + 2 entries
        unsigned* __restrict__ sbTotal,     // MAXSB entries
        unsigned* __restrict__ cursor0,     // zeroed; MAXSB entries
        unsigned* __restrict__ packed1,
        unsigned* __restrict__ packed2,
        unsigned* __restrict__ agg16u,
        int n4, int nE, int nbSB, int nN, int nChunks, int nGroups) {
    cg::grid_group grid = cg::this_grid();
    __shared__ SharedU sh;
    int t = threadIdx.x;
    int blk = blockIdx.x;
    int nBlk = gridDim.x;

    // ---- P1: fp32->bf16 conversion + per-node dst histogram + W frags ----
    for (int i = blk * 256 + t; i < n4; i += nBlk * 256) {
        float4 v = ((const float4*)nf)[i];
        bf16x4 o = { (__bf16)v.x, (__bf16)v.y, (__bf16)v.z, (__bf16)v.w };
        ((bf16x4*)nf16)[i] = o;
    }
    for (int e = blk * 256 + t; e < nE; e += nBlk * 256)
        atomicAdd(&nodecnt[dst[e]], 1u);     // 4B memory-side atomic (R1)
    if (blk == nBlk - 1) {
        // W[k][n] fp32 -> bf16 in MFMA-fragment order
        for (int idx = t; idx < 2 * D * D; idx += 256) {
            int k = idx >> 6, n = idx & 63;
            int ks = k >> 5, r = k & 31, quad = r >> 3, j = r & 7;
            int c = n >> 4, l16 = n & 15;
            int fidx = (((ks * 4 + c) * 64) + quad * 16 + l16) * 8 + j;
            wfrag[fidx] = (__bf16)W[idx];
        }
    }
    grid.sync();

    // ---- P2a: sbTotal[sb] = sum of nodecnt over its 512 nodes ----
    if (blk < nbSB) {
        unsigned a = nodecnt[blk * SBN + 2 * t] + nodecnt[blk * SBN + 2 * t + 1];
        sh.ts[t] = a; __syncthreads();
        for (int o = 128; o > 0; o >>= 1) {
            if (t < o) sh.ts[t] += sh.ts[t + o];
            __syncthreads();
        }
        if (t == 0) sbTotal[blk] = sh.ts[0];
    }
    grid.sync();

    // ---- P2b (blocks < nbSB): nodestart = global CSR row pointers ----
    if (blk < nbSB) {
        unsigned part = (t < blk) ? sbTotal[t] : 0u;   // nbSB <= 256
        sh.ts[t] = part; __syncthreads();
        for (int o = 128; o > 0; o >>= 1) {
            if (t < o) sh.ts[t] += sh.ts[t + o];
            __syncthreads();
        }
        unsigned sbBase = sh.ts[0];
        __syncthreads();
        unsigned a0 = nodecnt[blk * SBN + 2 * t];
        unsigned a1 = nodecnt[blk * SBN + 2 * t + 1];
        unsigned s = a0 + a1;
        sh.ts[t] = s; __syncthreads();
        for (int o = 1; o < 256; o <<= 1) {
            unsigned x = (t >= o) ? sh.ts[t - o] : 0u;
            __syncthreads();
            sh.ts[t] += x;
            __syncthreads();
        }
        unsigned ex = sh.ts[t] - s;
        nodestart[blk * SBN + 2 * t]     = sbBase + ex;
        nodestart[blk * SBN + 2 * t + 1] = sbBase + ex + a0;
        __syncthreads();
    }
    // (no grid sync needed: P3 uses sbTotal, not nodestart)

    // ---- P3: chunk scatter -> SB-sorted packed1 (coalesced flush) ----
    {
        unsigned g = (t < nbSB) ? sbTotal[t] : 0u;
        sh.p3.ts2[t] = g; __syncthreads();
        for (int o = 1; o < 256; o <<= 1) {
            unsigned x = (t >= o) ? sh.p3.ts2[t - o] : 0u;
            __syncthreads();
            sh.p3.ts2[t] += x;
            __syncthreads();
        }
        unsigned myBase = sh.p3.ts2[t] - g;   // exclusive SB prefix (t<nbSB)
        __syncthreads();

        for (int ch = blk; ch < nChunks; ch += nBlk) {
            int e0 = ch * SCHUNK;
            int ec = nE - e0; if (ec > SCHUNK) ec = SCHUNK;
            if (t < MAXSB) sh.p3.cop[t] = 0;
            __syncthreads();
            for (int i = t; i < ec; i += 256)
                atomicAdd(&sh.p3.cop[dst[e0 + i] >> SBSHIFT], 1u);
            __syncthreads();
            unsigned c = (t < nbSB) ? (sh.p3.cop[t] & 0xFFFFu) : 0u;
            sh.p3.ts2[t] = c; __syncthreads();
            for (int o = 1; o < 256; o <<= 1) {
                unsigned x = (t >= o) ? sh.p3.ts2[t - o] : 0u;
                __syncthreads();
                sh.p3.ts2[t] += x;
                __syncthreads();
            }
            if (t < nbSB) {
                sh.p3.lb16[t] = (unsigned short)(sh.p3.ts2[t] - c);
                if (c) sh.p3.gbase[t] = myBase + atomicAdd(&cursor0[t], c);
            }
            __syncthreads();
            for (int i = t; i < ec; i += 256) {
                int e = e0 + i;
                int d = dst[e];
                int b = d >> SBSHIFT;
                unsigned p = atomicAdd(&sh.p3.cop[b], 0x10000u) >> 16;
                unsigned pos = (unsigned)sh.p3.lb16[b] + p;
                sh.p3.payload[pos] = ((unsigned)(d & (SBN - 1)) << 17) | (unsigned)src[e];
                sh.p3.sbid[pos] = (unsigned char)b;
            }
            __syncthreads();
            for (int i = t; i < ec; i += 256) {
                unsigned b = sh.p3.sbid[i];
                packed1[sh.p3.gbase[b] + ((unsigned)i - (unsigned)sh.p3.lb16[b])]
                    = sh.p3.payload[i];
            }
            __syncthreads();
        }
    }
    grid.sync();   // packed1 + nodestart complete

    // ---- P4: per-SB counting scatter to node order (no count pass) ----
    for (int sb = blk; sb < nbSB; sb += nBlk) {
        unsigned beg = nodestart[sb * SBN];
        unsigned cnt = sbTotal[sb];
        sh.cur[2 * t]     = nodestart[sb * SBN + 2 * t];
        sh.cur[2 * t + 1] = nodestart[sb * SBN + 2 * t + 1];
        __syncthreads();
        for (unsigned i = beg + t; i < beg + cnt; i += 256) {
            unsigned e = packed1[i];
            unsigned p = atomicAdd(&sh.cur[e >> 17], 1u);
            packed2[p] = e & 0x1FFFFu;   // writes confined to SB's 32KB window
        }
        __syncthreads();
    }
    grid.sync();   // packed2 complete

    // ---- P5: direct segmax over CSR runs (R11-validated body) ----
    // NOTE: every __shfl must execute with ALL 64 lanes active (R9 bug);
    // tails clamp the index (dup edge; max idempotent).
    {
        const unsigned* nfu = (const unsigned*)nf16;
        int wv = t >> 6, ln = t & 63;
        int half = ln >> 5, dln = ln & 31;
        for (int grp = blk; grp < nGroups; grp += nBlk) {
            int n0 = grp * (4 * NPW) + wv * NPW;
            #pragma unroll 1
            for (int k = 0; k < NPW; ++k) {
                int n = n0 + k;                          // wave-uniform
                if (n >= nN) break;
                unsigned rb = nodestart[n], re = nodestart[n + 1];
                unsigned m0 = 0, m1 = 0, m2 = 0, m3 = 0;
                for (unsigned c = rb; c < re; c += 64) {
                    unsigned idx = c + (unsigned)ln;
                    unsigned pe = (idx < re) ? packed2[idx] : 0u;
                    int lim = (int)(re - c); if (lim > 64) lim = 64;
                    int j = 0;
                    for (; j + 8 <= lim; j += 8) {
                        unsigned sa = __shfl(pe, j + half, 64);
                        unsigned sb = __shfl(pe, j + 2 + half, 64);
                        unsigned sc = __shfl(pe, j + 4 + half, 64);
                        unsigned sd = __shfl(pe, j + 6 + half, 64);
                        unsigned g0 = nfu[(size_t)sa * 32 + dln];
                        unsigned g1 = nfu[(size_t)sb * 32 + dln];
                        unsigned g2 = nfu[(size_t)sc * 32 + dln];
                        unsigned g3 = nfu[(size_t)sd * 32 + dln];
                        m0 = pkmax(m0, pk_ord_encode(g0));
                        m1 = pkmax(m1, pk_ord_encode(g1));
                        m2 = pkmax(m2, pk_ord_encode(g2));
                        m3 = pkmax(m3, pk_ord_encode(g3));
                    }
                    for (; j + 4 <= lim; j += 4) {
                        unsigned sa = __shfl(pe, j + half, 64);
                        unsigned sb = __shfl(pe, j + 2 + half, 64);
                        unsigned g0 = nfu[(size_t)sa * 32 + dln];
                        unsigned g1 = nfu[(size_t)sb * 32 + dln];
                        m0 = pkmax(m0, pk_ord_encode(g0));
                        m1 = pkmax(m1, pk_ord_encode(g1));
                    }
                    for (; j < lim; j += 2) {
                        int jj = j + half;
                        if (jj >= lim) jj = lim - 1;    // dup tail, convergent
                        unsigned g = nfu[(size_t)__shfl(pe, jj, 64) * 32 + dln];
                        m0 = pkmax(m0, pk_ord_encode(g));
                    }
                }
                unsigned m = pkmax(pkmax(m0, m1), pkmax(m2, m3));
                m = pkmax(m, __shfl_xor(m, 32, 64));
                if (ln < 32) {
                    unsigned raw = pk_ord_decode(m);    // empty -> NaN halves
                    unsigned xr  = nfu[(size_t)n * 32 + dln];
                    float v0 = __uint_as_float(raw << 16);
                    float v1 = __uint_as_float(raw & 0xFFFF0000u);
                    float x0 = __uint_as_float(xr << 16);
                    float x1 = __uint_as_float(xr & 0xFFFF0000u);
                    float r0 = v0 - x0; r0 = (r0 >= CLAMP_V) ? r0 : 0.0f;
                    float r1 = v1 - x1; r1 = (r1 >= CLAMP_V) ? r1 : 0.0f;
                    __bf16 b0 = (__bf16)r0, b1 = (__bf16)r1;
                    unsigned o = ((unsigned)__builtin_bit_cast(unsigned short, b1) << 16)
                               |  (unsigned)__builtin_bit_cast(unsigned short, b0);
                    agg16u[(size_t)n * 32 + dln] = o;
                }
            }
        }
    }
}

// ---------------- pass E: MFMA MLP (unchanged, validated) ----------------
__global__ __launch_bounds__(256) void node_mlp_mfma(
        const __bf16* __restrict__ nf16,
        const __bf16* __restrict__ agg16,
        float* __restrict__ out,
        const __bf16* __restrict__ wfrag,
        const float* __restrict__ bias,
        int nTiles, int nN) {
    int lane = threadIdx.x & 63;
    int quad = lane >> 4;
    int l16  = lane & 15;
    int waveGlobal = blockIdx.x * 4 + (threadIdx.x >> 6);
    int nWaves = gridDim.x * 4;

    bf16x8 bfrag[4][4];
    #pragma unroll
    for (int c = 0; c < 4; ++c)
        #pragma unroll
        for (int ks = 0; ks < 4; ++ks)
            bfrag[c][ks] = *(const bf16x8*)(wfrag + ((size_t)((ks * 4 + c) * 64 + lane)) * 8);
    float bv[4];
    #pragma unroll
    for (int c = 0; c < 4; ++c) bv[c] = bias[c * 16 + l16];

    for (int t = waveGlobal; t < nTiles; t += nWaves) {
        int n0 = t * 16;
        int rowA = n0 + l16;
        if (rowA >= nN) rowA = nN - 1;
        const __bf16* nfr = nf16  + (size_t)rowA * D;
        const __bf16* agr = agg16 + (size_t)rowA * D;

        floatx4 acc[4] = {{0,0,0,0},{0,0,0,0},{0,0,0,0},{0,0,0,0}};
        #pragma unroll
        for (int ks = 0; ks < 4; ++ks) {
            const __bf16* p = (ks < 2) ? (nfr + ks * 32 + quad * 8)
                                       : (agr + (ks - 2) * 32 + quad * 8);
            bf16x8 a = *(const bf16x8*)p;
            #pragma unroll
            for (int c = 0; c < 4; ++c)
                acc[c] = __builtin_amdgcn_mfma_f32_16x16x32_bf16(
                             a, bfrag[c][ks], acc[c], 0, 0, 0);
        }
        #pragma unroll
        for (int r = 0; r < 4; ++r) {
            int row = n0 + quad * 4 + r;
            if (row < nN) {
                #pragma unroll
                for (int c = 0; c < 4; ++c) {
                    float vv = acc[c][r] + bv[c];
                    out[(size_t)row * D + c * 16 + l16] = fmaxf(vv, 0.0f);
                }
            }
        }
    }
}

extern "C" void kernel_launch(void* const* d_in, const int* in_sizes, int n_in,
                              void* d_out, int out_size, void* d_ws, size_t ws_size,
                              hipStream_t stream) {
    const float* nf  = (const float*)d_in[0];
    const int*   src = (const int*)d_in[1];
    const int*   dst = (const int*)d_in[2];
    const float* W   = (const float*)d_in[3];
    const float* b   = (const float*)d_in[4];
    float* out = (float*)d_out;

    int nN = in_sizes[0] / D;
    int nE = in_sizes[1];
    int nbSB = (nN + SBN - 1) / SBN;            // 196

    // ws layout
    char* wsb = (char*)d_ws;
    size_t nfB  = (((size_t)nN * D * 2) + 255) & ~(size_t)255;  // 12.8 MB
    size_t pkB  = (((size_t)nE * 4)     + 255) & ~(size_t)255;  // 6.4 MB
    size_t ncB  = (((size_t)nbSB * SBN * 4) + 255) & ~(size_t)255;
    __bf16*   nf16      = (__bf16*)wsb;
    __bf16*   agg16     = (__bf16*)(wsb + nfB);
    unsigned* packed1   = (unsigned*)(wsb + 2 * nfB);
    unsigned* nodecnt   = (unsigned*)(wsb + 2 * nfB + pkB);
    unsigned* cursor0   = (unsigned*)(wsb + 2 * nfB + pkB + ncB);      // right after
    unsigned* nodestart = (unsigned*)(wsb + 2 * nfB + pkB + ncB + 4 * MAXSB);
    unsigned* sbTotal   = (unsigned*)(wsb + 2 * nfB + pkB + 2 * ncB + 4 * MAXSB + 256);
    __bf16*   wfrag     = (__bf16*)(wsb + 2 * nfB + pkB + 2 * ncB + 8 * MAXSB + 512);
    // packed2 lives in d_out: consumed in P5 before the MLP overwrites out
    unsigned* packed2 = (unsigned*)d_out;

    // zero nodecnt + cursor0 (adjacent)
    hipMemsetAsync(nodecnt, 0, ncB + 4 * MAXSB, stream);

    int n4 = nN * D / 4;                        // 1.6M
    int nChunks = (nE + SCHUNK - 1) / SCHUNK;   // 782
    int nGroups = (nN + 4 * NPW - 1) / (4 * NPW); // 3125

    __bf16* nf16p = nf16;
    void* args[] = {
        (void*)&nf, (void*)&nf16p, (void*)&src, (void*)&dst, (void*)&W,
        (void*)&wfrag, (void*)&nodecnt, (void*)&nodestart, (void*)&sbTotal,
        (void*)&cursor0, (void*)&packed1, (void*)&packed2, (void*)&agg16,
        (void*)&n4, (void*)&nE, (void*)&nbSB, (void*)&nN,
        (void*)&nChunks, (void*)&nGroups
    };
    hipLaunchCooperativeKernel((void*)fused_kernel, dim3(GRIDC), dim3(256),
                               args, 0, stream);

    int nTiles = (nN + 15) / 16;
    node_mlp_mfma<<<768, 256, 0, stream>>>(nf16, agg16, out, wfrag, b, nTiles, nN);
}